// Round 16
// baseline (66.035 us; speedup 1.0000x reference)
//
#include <hip/hip_runtime.h>

// AdaptiveConv: out[b,c,h,w] = sum_{idx<25} x[b,c,h+idx/5, w+idx%5] * kernel[b,idx,h,w]
// Shapes: x (8,64,260,260) f32, kernel (8,25,256,256) f32, out (8,64,256,256) f32.
//
// R15: R10/R11/R13/R14 all plateau at 65-72us. Budget: vec-mem ~37us (taps
// dominate at CH=4) + LDS ~25.6us, barely overlapped. Lever: CH=8 halves the
// tap stream; full-W CH=8 needs 66.6KB (R9: 2 blk/CU, no win), so W-SPLIT:
// tile = 128 cols x 8 rows x 8 ch -> 52.2KB LDS -> 3 blk/CU, 12 waves/CU.
// Per-output-f4 vec-mem 9.5 -> 5.7 f4-loads (taps 6.25->3.125, halo 2x->1.5x).
// Inner FMA shape (f4 cols, 2 LDS reads/ch/i, 5-tap f4 rows) frozen from R10.
// Swizzle: cg fastest; XCD r owns batch b=r; per-hblk working set ~1MB << L2.

constexpr int K  = 5;
constexpr int B  = 8;
constexpr int C  = 64;
constexpr int H  = 256;
constexpr int W  = 256;
constexpr int HX = H + K - 1;   // 260
constexpr int WX = W + K - 1;   // 260

constexpr int CH  = 8;          // channels per block (tap amortization /8)
constexpr int NCG = C / CH;     // 8 channel groups
constexpr int HPB = 8;          // output rows per block
constexpr int NHB = H / HPB;    // 32 h-blocks
constexpr int WPB = 128;        // output cols per block
constexpr int NWS = W / WPB;    // 2 width splits
constexpr int NWG = NCG * NWS * NHB * B;  // 4096 blocks

constexpr int XR       = HPB + K - 1;     // 12 staged x-rows
constexpr int SROW_F4  = 34;              // f4 per staged row (33 used + 1 pad)
constexpr int STAGE_F4 = CH * XR * 33;    // 3168 staged f4 (pad not staged)
// LDS: 8 ch x 12 rows x 136 floats x 4B = 52,224 B -> 3 blocks/CU.

typedef float f4 __attribute__((ext_vector_type(4)));

__global__ __launch_bounds__(256, 3)
void adaptive_conv_kernel(const float* __restrict__ x,
                          const float* __restrict__ kern,
                          float* __restrict__ out) {
    __shared__ float xs[CH][XR][SROW_F4 * 4];

    // XCD-aware swizzle (bijective: NWG % 8 == 0). cg fastest -> the 8 blocks
    // sharing one kern tile are consecutive on one XCD; b == XCD id, so each
    // XCD's L2 holds one image's rolling window (~1MB per hblk).
    const int k    = blockIdx.x;
    const int orig = (k & 7) * (NWG / 8) + (k >> 3);
    const int cg   = orig & (NCG - 1);          // channel group (fastest)
    const int ws   = (orig >> 3) & (NWS - 1);   // width split
    const int hblk = (orig >> 4) & (NHB - 1);   // h-block
    const int b    = orig >> 9;                 // batch (slowest)

    const int tid = threadIdx.x;
    const int r8  = tid >> 5;               // 0..7: output row within block
    const int cp  = tid & 31;               // col group within 128-col span
    const int w0l = cp * 4;                 // local col base (16B aligned)
    const int wg0 = ws * WPB;               // 0 or 128
    const int h   = hblk * HPB + r8;        // output row
    const int c0  = cg * CH;                // channel base

    const size_t xplane = (size_t)HX * WX;

    // ---- stage x[b, c0:c0+8, h0:h0+12, wg0:wg0+132] -> LDS (52.2 KB) ----
    // Flat-indexed: 3168 f4, 13 sweeps of 256 threads. Row stride padded to
    // 34 f4 (pad f4 never written/read). Max global col = wg0+131 <= 259,
    // max row = hblk*8+11 <= 259: no OOB by construction.
    {
        const float* xg = x + ((size_t)b * C + c0) * xplane
                            + (size_t)(hblk * HPB) * WX + wg0;
        #pragma unroll
        for (int it = 0; it < 13; ++it) {
            const int idx = it * 256 + tid;
            if (idx < STAGE_F4) {
                const int ch  = idx / (XR * 33);            // magic-mul div
                const int rem = idx - ch * (XR * 33);
                const int rr  = rem / 33;
                const int s   = rem - rr * 33;
                f4 v = *(const f4*)(xg + (size_t)ch * xplane + rr * WX + s * 4);
                *(f4*)&xs[ch][rr][s * 4] = v;
            }
        }
    }
    __syncthreads();

    const float* kb = kern + (size_t)b * (K * K * H * W)
                           + (size_t)h * W + wg0 + w0l;

    f4 acc[CH];
    #pragma unroll
    for (int ch = 0; ch < CH; ++ch) acc[ch] = (f4)0.0f;

    #pragma unroll
    for (int i = 0; i < K; ++i) {
        // Tap row i: 5 f4 (my 4 cols, j=0..4), reused across 8 channels.
        f4 t[K];
        #pragma unroll
        for (int j = 0; j < K; ++j) {
            t[j] = *(const f4*)(kb + (size_t)(i * K + j) * (H * W));
        }

        #pragma unroll
        for (int ch = 0; ch < CH; ++ch) {
            // x row (r8+i), local cols w0l..w0l+7 from LDS. 544B row stride,
            // 16B/lane contiguous within each 32-lane row-half: conflict-free.
            const float* xr_ = &xs[ch][r8 + i][w0l];
            f4 xa  = *(const f4*)(xr_);
            f4 xcv = *(const f4*)(xr_ + 4);
            float xsg[8] = {xa.x, xa.y, xa.z, xa.w, xcv.x, xcv.y, xcv.z, xcv.w};

            #pragma unroll
            for (int j = 0; j < K; ++j) {      // static indices only (rule #20)
                acc[ch].x = fmaf(xsg[j + 0], t[j].x, acc[ch].x);
                acc[ch].y = fmaf(xsg[j + 1], t[j].y, acc[ch].y);
                acc[ch].z = fmaf(xsg[j + 2], t[j].z, acc[ch].z);
                acc[ch].w = fmaf(xsg[j + 3], t[j].w, acc[ch].w);
            }
        }
    }

    float* ob = out + ((size_t)b * C + c0) * (H * W) + (size_t)h * W + wg0 + w0l;
    #pragma unroll
    for (int ch = 0; ch < CH; ++ch) {
        // out written once, never read: bypass caches (keep x+kern resident).
        __builtin_nontemporal_store(acc[ch], (f4*)(ob + (size_t)ch * (H * W)));
    }
}

extern "C" void kernel_launch(void* const* d_in, const int* in_sizes, int n_in,
                              void* d_out, int out_size, void* d_ws, size_t ws_size,
                              hipStream_t stream) {
    const float* x    = (const float*)d_in[0];
    const float* kern = (const float*)d_in[1];
    float*       out  = (float*)d_out;

    dim3 grid(NWG);      // 4096 blocks, 1D; decode + swizzle in-kernel
    dim3 block(256);     // 8 rows x 32 col-groups
    adaptive_conv_kernel<<<grid, block, 0, stream>>>(x, kern, out);
}